// Round 19
// baseline (532.144 us; speedup 1.0000x reference)
//
#include <hip/hip_runtime.h>
#include <math.h>

typedef _Float16 f16;
typedef f16 f16x8 __attribute__((ext_vector_type(8)));
typedef float f32x4 __attribute__((ext_vector_type(4)));

// quantization of y = s/2 - provisional_center: window [-2.5, +1.5]
#define QSCALE 16384.0f
#define QINV 6.103515625e-5f
#define QOFF 2.5f

__device__ __forceinline__ float wred_add(float v) {
#pragma unroll
  for (int off = 32; off >= 1; off >>= 1) v += __shfl_xor(v, off, 64);
  return v;
}
__device__ __forceinline__ float wred_max(float v) {
#pragma unroll
  for (int off = 32; off >= 1; off >>= 1) v = fmaxf(v, __shfl_xor(v, off, 64));
  return v;
}

// ---------------- LayerNorm row stats (hidden + memory in one launch) ----
__global__ __launch_bounds__(256) void ln_stats_all_kernel(
    const float* __restrict__ hidden, const float* __restrict__ memory,
    float* __restrict__ mu_h, float* __restrict__ rs_h,
    float* __restrict__ mu_m, float* __restrict__ rs_m) {
  int b = blockIdx.x, tid = threadIdx.x;
  const float* X;
  float* mu;
  float* rs;
  int cols, row;
  if (b < 1024) { X = hidden; cols = 2048; mu = mu_h; rs = rs_h; row = b; }
  else { X = memory; cols = 1024; mu = mu_m; rs = rs_m; row = b - 1024; }
  const float4* xr = (const float4*)(X + (size_t)row * cols);
  int nv = cols >> 10;
  float s = 0.f, s2 = 0.f;
  for (int v = 0; v < nv; ++v) {
    float4 x4 = xr[tid + (v << 8)];
    s += x4.x + x4.y + x4.z + x4.w;
    s2 += x4.x * x4.x + x4.y * x4.y + x4.z * x4.z + x4.w * x4.w;
  }
  s = wred_add(s);
  s2 = wred_add(s2);
  __shared__ float rb[8];
  int wid = tid >> 6, lane = tid & 63;
  if (lane == 0) { rb[wid] = s; rb[4 + wid] = s2; }
  __syncthreads();
  if (tid == 0) {
    float S = rb[0] + rb[1] + rb[2] + rb[3];
    float S2 = rb[4] + rb[5] + rb[6] + rb[7];
    float m = S / (float)cols;
    float var = S2 / (float)cols - m * m;
    mu[row] = m;
    rs[row] = 1.f / sqrtf(var + 1e-5f);
  }
}

// ---------------- split A (hidden + memory) in one launch ----------------
__global__ __launch_bounds__(256) void split_a_all_kernel(
    const float* __restrict__ hidden, const float* __restrict__ memory,
    const float* __restrict__ mu_h, const float* __restrict__ rs_h,
    const float* __restrict__ mu_m, const float* __restrict__ rs_m,
    f16x8* __restrict__ Ahh, f16x8* __restrict__ Ahl,
    f16x8* __restrict__ Amh, f16x8* __restrict__ Aml) {
  int b = blockIdx.x;
  const float* X;
  const float* mu;
  const float* rs;
  f16x8 *Ah, *Al;
  int M, Kd, b0;
  if (b < 1024) {
    X = hidden; mu = mu_h; rs = rs_h; Ah = Ahh; Al = Ahl;
    M = 1024; Kd = 2048; b0 = 0;
  } else {
    X = memory; mu = mu_m; rs = rs_m; Ah = Amh; Al = Aml;
    M = 8192; Kd = 1024; b0 = 1024;
  }
  int blk = (b - b0) * 4 + (threadIdx.x >> 6);
  int l = threadIdx.x & 63;
  int nmt = M >> 4;
  int kc = blk / nmt, mt = blk - kc * nmt;
  int m = mt * 16 + (l & 15);
  int k = kc * 32 + ((l >> 4) << 3);
  const float* src = X + (size_t)m * Kd + k;
  float mm = mu[m];
  float rr = rs[m];
  f16x8 hi, lo;
#pragma unroll
  for (int j = 0; j < 8; ++j) {
    float v = (src[j] - mm) * rr;
    f16 hv = (f16)v;
    hi[j] = hv;
    lo[j] = (f16)((v - (float)hv) * 512.f);
  }
  size_t o = ((size_t)blk << 6) + l;
  Ah[o] = hi;
  Al[o] = lo;
}

// ---------------- split A for xi (epilogue) ----------------
__global__ __launch_bounds__(256) void split_a_kernel(
    const float* __restrict__ X, const float* __restrict__ mu,
    const float* __restrict__ rs, f16x8* __restrict__ Ah,
    f16x8* __restrict__ Al, int M, int Kd, int lay) {
  int blk = blockIdx.x * 4 + (threadIdx.x >> 6);
  int l = threadIdx.x & 63;
  int nmt = M >> 4;
  int kc = blk / nmt, mt = blk - kc * nmt;
  int m = mt * 16 + (l & 15);
  int k = kc * 32 + ((l >> 4) << 3);
  const float* src;
  if (lay == 0) {
    src = X + (size_t)m * Kd + k;
  } else {
    int b = m >> 9, s = m & 511, hh = k >> 6, d = k & 63;
    src = X + ((((size_t)b * 4 + hh) * 512 + s) << 6) + d;
  }
  float mm = mu ? mu[m] : 0.f;
  float rr = rs ? rs[m] : 1.f;
  f16x8 hi, lo;
#pragma unroll
  for (int j = 0; j < 8; ++j) {
    float v = (src[j] - mm) * rr;
    f16 hv = (f16)v;
    hi[j] = hv;
    lo[j] = (f16)((v - (float)hv) * 512.f);
  }
  size_t o = ((size_t)blk << 6) + l;
  Ah[o] = hi;
  Al[o] = lo;
}

// ---------------- split W: all four weights in one launch ----------------
__global__ __launch_bounds__(256) void split_w_all_kernel(
    const float* __restrict__ Wq, const float* __restrict__ Wk,
    const float* __restrict__ Wv, const float* __restrict__ Wo,
    const float* __restrict__ g_s, const float* __restrict__ g_m,
    f16x8* __restrict__ Bqh, f16x8* __restrict__ Bql,
    f16x8* __restrict__ Bkh, f16x8* __restrict__ Bkl,
    f16x8* __restrict__ Bvh, f16x8* __restrict__ Bvl,
    f16x8* __restrict__ Boh, f16x8* __restrict__ Bol) {
  int b = blockIdx.x;
  const float* W;
  const float* g;
  f16x8 *Bh, *Bl;
  int N, base;
  if (b < 256) { W = Wq; g = g_s; Bh = Bqh; Bl = Bql; N = 256; base = 0; }
  else if (b < 384) { W = Wk; g = g_m; Bh = Bkh; Bl = Bkl; N = 256; base = 256; }
  else if (b < 512) { W = Wv; g = g_m; Bh = Bvh; Bl = Bvl; N = 256; base = 384; }
  else { W = Wo; g = nullptr; Bh = Boh; Bl = Bol; N = 2048; base = 512; }
  int blk = (b - base) * 4 + (threadIdx.x >> 6);
  int l = threadIdx.x & 63;
  int nnt = N >> 4;
  int kc = blk / nnt, nt = blk - kc * nnt;
  int n = nt * 16 + (l & 15);
  int k0 = kc * 32 + ((l >> 4) << 3);
  f16x8 hi, lo;
#pragma unroll
  for (int j = 0; j < 8; ++j) {
    float v = W[(size_t)(k0 + j) * N + n];
    if (g) v *= g[k0 + j];
    f16 hv = (f16)v;
    hi[j] = hv;
    lo[j] = (f16)((v - (float)hv) * 512.f);
  }
  size_t o = ((size_t)blk << 6) + l;
  Bh[o] = hi;
  Bl[o] = lo;
}

// ---------------- vb[t] = sum_k b[k]*W[k][t], 3 targets in one ----------
__global__ __launch_bounds__(256) void wcol3_kernel(
    const float* __restrict__ Wq, const float* __restrict__ bq,
    const float* __restrict__ Wk, const float* __restrict__ bk,
    const float* __restrict__ Wv, const float* __restrict__ bv,
    float* __restrict__ vbq, float* __restrict__ vbk,
    float* __restrict__ vbv) {
  int which = blockIdx.z;
  const float* W = which == 0 ? Wq : (which == 1 ? Wk : Wv);
  const float* b = which == 0 ? bq : (which == 1 ? bk : bv);
  float* vb = which == 0 ? vbq : (which == 1 ? vbk : vbv);
  int Kd = which == 0 ? 2048 : 1024;
  int t = threadIdx.x;
  int kpb = Kd >> 4;
  int k0 = blockIdx.y * kpb;
  float s = 0.f;
  for (int k = k0; k < k0 + kpb; ++k) s = fmaf(b[k], W[(size_t)k * 256 + t], s);
  atomicAdd(&vb[t], s);
}

// ---------------- split-f16 MFMA GEMM: C = A@W + vb ----------------
__global__ __launch_bounds__(256) void gemm_mfma_kernel(
    const f16x8* __restrict__ Ah, const f16x8* __restrict__ Al,
    const f16x8* __restrict__ Bh, const f16x8* __restrict__ Bl,
    const float* __restrict__ vb, float* __restrict__ outf,
    f16x8* __restrict__ o16a, f16x8* __restrict__ o16b, int M, int N, int nk,
    int out_mode) {
  __shared__ __align__(16) float Ts[64][68];
  const int tid = threadIdx.x;
  const int w = tid >> 6, l = tid & 63;
  const int ql = l & 15, g = l >> 4;
  const int bn = blockIdx.x, bm = blockIdx.y;
  const size_t astr = ((size_t)(M >> 4)) << 6;
  const size_t bstr = ((size_t)(N >> 4)) << 6;
  const f16x8* aph = Ah + (((size_t)(bm * 4 + w)) << 6) + l;
  const f16x8* apl = Al + (((size_t)(bm * 4 + w)) << 6) + l;
  const f16x8* bph = Bh + (((size_t)(bn * 4)) << 6) + l;
  const f16x8* bpl = Bl + (((size_t)(bn * 4)) << 6) + l;

  f32x4 cm[4], cx[4];
#pragma unroll
  for (int nf = 0; nf < 4; ++nf) {
    cm[nf] = (f32x4){0.f, 0.f, 0.f, 0.f};
    cx[nf] = (f32x4){0.f, 0.f, 0.f, 0.f};
  }

  f16x8 a0h = aph[0], a0l = apl[0];
  f16x8 b0h[4], b0l[4];
#pragma unroll
  for (int nf = 0; nf < 4; ++nf) {
    b0h[nf] = bph[nf << 6];
    b0l[nf] = bpl[nf << 6];
  }

  for (int kc = 0; kc < nk - 1; ++kc) {
    const size_t ao = (size_t)(kc + 1) * astr;
    const size_t bo = (size_t)(kc + 1) * bstr;
    f16x8 a1h = aph[ao], a1l = apl[ao];
    f16x8 b1h[4], b1l[4];
#pragma unroll
    for (int nf = 0; nf < 4; ++nf) {
      b1h[nf] = bph[bo + (nf << 6)];
      b1l[nf] = bpl[bo + (nf << 6)];
    }
#pragma unroll
    for (int nf = 0; nf < 4; ++nf) {
      cm[nf] = __builtin_amdgcn_mfma_f32_16x16x32_f16(a0h, b0h[nf], cm[nf], 0, 0, 0);
      cx[nf] = __builtin_amdgcn_mfma_f32_16x16x32_f16(a0h, b0l[nf], cx[nf], 0, 0, 0);
      cx[nf] = __builtin_amdgcn_mfma_f32_16x16x32_f16(a0l, b0h[nf], cx[nf], 0, 0, 0);
    }
    a0h = a1h;
    a0l = a1l;
#pragma unroll
    for (int nf = 0; nf < 4; ++nf) {
      b0h[nf] = b1h[nf];
      b0l[nf] = b1l[nf];
    }
  }
#pragma unroll
  for (int nf = 0; nf < 4; ++nf) {
    cm[nf] = __builtin_amdgcn_mfma_f32_16x16x32_f16(a0h, b0h[nf], cm[nf], 0, 0, 0);
    cx[nf] = __builtin_amdgcn_mfma_f32_16x16x32_f16(a0h, b0l[nf], cx[nf], 0, 0, 0);
    cx[nf] = __builtin_amdgcn_mfma_f32_16x16x32_f16(a0l, b0h[nf], cx[nf], 0, 0, 0);
  }

  float vbc[4] = {0.f, 0.f, 0.f, 0.f};
  if (vb) {
#pragma unroll
    for (int nf = 0; nf < 4; ++nf) vbc[nf] = vb[bn * 64 + nf * 16 + ql];
  }

  if (out_mode == 0) {
#pragma unroll
    for (int nf = 0; nf < 4; ++nf)
#pragma unroll
      for (int r = 0; r < 4; ++r) {
        float val = fmaf(cx[nf][r], 0.001953125f, cm[nf][r]) + vbc[nf];
        int m = bm * 64 + w * 16 + (g << 2) + r;
        int n = bn * 64 + nf * 16 + ql;
        int b = m >> 9, s = m & 511, hh = n >> 6, d = n & 63;
        outf[((((size_t)b * 4 + hh) * 512 + s) << 6) + d] = val;
      }
  } else if (out_mode == 3) {
#pragma unroll
    for (int nf = 0; nf < 4; ++nf)
#pragma unroll
      for (int r = 0; r < 4; ++r) {
        float val = fmaf(cx[nf][r], 0.001953125f, cm[nf][r]) + vbc[nf];
        int m = bm * 64 + w * 16 + (g << 2) + r;
        int n = bn * 64 + nf * 16 + ql;
        outf[(size_t)m * N + n] = val;
      }
  } else {
#pragma unroll
    for (int nf = 0; nf < 4; ++nf)
#pragma unroll
      for (int r = 0; r < 4; ++r)
        Ts[w * 16 + (g << 2) + r][nf * 16 + ql] =
            fmaf(cx[nf][r], 0.001953125f, cm[nf][r]) + vbc[nf];
    __syncthreads();
    if (out_mode == 4) {
#pragma unroll
      for (int i = 0; i < 2; ++i) {
        int slot = tid + (i << 8);
        int blk = slot >> 6, l2 = slot & 63;
        int ktl = blk >> 1, dc = blk & 1;
        int key = (ktl << 4) + (l2 & 15);
        int db = (dc << 5) + ((l2 >> 4) << 3);
        f16x8 hi, lo;
#pragma unroll
        for (int j = 0; j < 8; ++j) {
          float v = Ts[key][db + j];
          f16 hv = (f16)v;
          hi[j] = hv;
          lo[j] = (f16)((v - (float)hv) * 512.f);
        }
        size_t o = (((size_t)(bn * 512 + bm * 4 + ktl) * 2 + dc) << 6) + l2;
        o16a[o] = hi;
        o16b[o] = lo;
      }
    } else {
#pragma unroll
      for (int i = 0; i < 2; ++i) {
        int slot = tid + (i << 8);
        int blk = slot >> 6, l2 = slot & 63;
        int dt = blk >> 1, kcl = blk & 1;
        int keyb = (kcl << 5) + ((l2 >> 4) << 3);
        int d = (dt << 4) + (l2 & 15);
        f16x8 v8;
#pragma unroll
        for (int j = 0; j < 8; ++j) v8[j] = (f16)Ts[keyb + j][d];
        size_t o = (((size_t)(bn * 4 + dt) * 256 + bm * 2 + kcl) << 6) + l2;
        o16a[o] = v8;
      }
    }
  }
}

// ------- S1: scores; 2 qtiles (32 rows) x half the keys per block -------
__global__ __launch_bounds__(1024) void hop_score_kernel(
    const float* __restrict__ xi_in, const f16x8* __restrict__ Khi,
    const f16x8* __restrict__ Klo, const float* __restrict__ log_beta,
    unsigned short* __restrict__ Y) {
  __shared__ float xiq[32][64];
  __shared__ float mxb[16][32];
  __shared__ float mxs[32];
  const int tid = threadIdx.x;
  const int w = tid >> 6, l = tid & 63;
  const int ql = l & 15, g = l >> 4;
  const int bh = blockIdx.x & 7;
  const int qpair = (blockIdx.x >> 3) & 15;
  const int khalf = blockIdx.x >> 7;
  const int h = bh & 3;
  const size_t base_io = ((size_t)bh * 512 + qpair * 32) * 64;

  float beta = expf(log_beta[h]);
  for (int i = tid; i < 2048; i += 1024)
    xiq[i >> 6][i & 63] = xi_in[base_io + i] * beta;
  __syncthreads();

  f16x8 xa0, xa1, xla0, xla1;  // qtile A (rows ql)
  f16x8 xb0, xb1, xlb0, xlb1;  // qtile B (rows 16+ql)
#pragma unroll
  for (int j = 0; j < 8; ++j) {
    float a0v = xiq[ql][(g << 3) + j];
    float a1v = xiq[ql][32 + (g << 3) + j];
    float b0v = xiq[16 + ql][(g << 3) + j];
    float b1v = xiq[16 + ql][32 + (g << 3) + j];
    f16 ha0 = (f16)a0v, ha1 = (f16)a1v, hb0 = (f16)b0v, hb1 = (f16)b1v;
    xa0[j] = ha0; xla0[j] = (f16)((a0v - (float)ha0) * 512.f);
    xa1[j] = ha1; xla1[j] = (f16)((a1v - (float)ha1) * 512.f);
    xb0[j] = hb0; xlb0[j] = (f16)((b0v - (float)hb0) * 512.f);
    xb1[j] = hb1; xlb1[j] = (f16)((b1v - (float)hb1) * 512.f);
  }

  const f16x8* kb = Khi + (size_t)h * 65536 + l;
  const f16x8* kl = Klo + (size_t)h * 65536 + l;

  // sample at kt = w*32 (khalf-independent -> identical centers)
  {
    const int kts = w * 32;
    f16x8 sa0 = kb[(size_t)kts * 128], sa1 = kb[(size_t)kts * 128 + 64];
    f32x4 cA = {0.f, 0.f, 0.f, 0.f}, cB = {0.f, 0.f, 0.f, 0.f};
    cA = __builtin_amdgcn_mfma_f32_16x16x32_f16(sa0, xa0, cA, 0, 0, 0);
    cA = __builtin_amdgcn_mfma_f32_16x16x32_f16(sa1, xa1, cA, 0, 0, 0);
    cB = __builtin_amdgcn_mfma_f32_16x16x32_f16(sa0, xb0, cB, 0, 0, 0);
    cB = __builtin_amdgcn_mfma_f32_16x16x32_f16(sa1, xb1, cB, 0, 0, 0);
    float mA = fmaxf(fmaxf(cA[0], cA[1]), fmaxf(cA[2], cA[3]));
    float mB = fmaxf(fmaxf(cB[0], cB[1]), fmaxf(cB[2], cB[3]));
    mA = fmaxf(mA, __shfl_xor(mA, 16, 64));
    mA = fmaxf(mA, __shfl_xor(mA, 32, 64));
    mB = fmaxf(mB, __shfl_xor(mB, 16, 64));
    mB = fmaxf(mB, __shfl_xor(mB, 32, 64));
    if (l < 16) { mxb[w][ql] = mA; mxb[w][16 + ql] = mB; }
  }
  __syncthreads();
  if (tid < 32) {
    float m = mxb[0][tid];
#pragma unroll
    for (int ww = 1; ww < 16; ++ww) m = fmaxf(m, mxb[ww][tid]);
    mxs[tid] = m;
  }
  __syncthreads();
  const float qcA = QOFF * QSCALE + 0.5f - mxs[ql] * 0.5f * QSCALE;
  const float qcB = QOFF * QSCALE + 0.5f - mxs[16 + ql] * 0.5f * QSCALE;

  const size_t YbaseA = (size_t)(bh * 32 + qpair * 2) * 131072;
  const size_t YbaseB = YbaseA + 131072;
  const int kt0 = khalf * 256 + w * 16;
  for (int kt = kt0; kt < kt0 + 16; ++kt) {
    f16x8 a0 = kb[(size_t)kt * 128], a1 = kb[(size_t)kt * 128 + 64];
    f16x8 b0 = kl[(size_t)kt * 128], b1 = kl[(size_t)kt * 128 + 64];
    const size_t yoff =
        (size_t)(kt >> 1) * 512 + ql * 32 + (kt & 1) * 16 + (g << 2);
    // qtile A
    {
      f32x4 cm = {0.f, 0.f, 0.f, 0.f}, cx = {0.f, 0.f, 0.f, 0.f};
      cm = __builtin_amdgcn_mfma_f32_16x16x32_f16(a0, xa0, cm, 0, 0, 0);
      cm = __builtin_amdgcn_mfma_f32_16x16x32_f16(a1, xa1, cm, 0, 0, 0);
      cx = __builtin_amdgcn_mfma_f32_16x16x32_f16(b0, xa0, cx, 0, 0, 0);
      cx = __builtin_amdgcn_mfma_f32_16x16x32_f16(a0, xla0, cx, 0, 0, 0);
      cx = __builtin_amdgcn_mfma_f32_16x16x32_f16(b1, xa1, cx, 0, 0, 0);
      cx = __builtin_amdgcn_mfma_f32_16x16x32_f16(a1, xla1, cx, 0, 0, 0);
      ushort4 uv;
      unsigned short* up = (unsigned short*)&uv;
#pragma unroll
      for (int r = 0; r < 4; ++r) {
        float s = fmaf(cx[r], 0.001953125f, cm[r]);
        float uq = fmaf(s, 8192.0f, qcA);
        uq = fminf(fmaxf(uq, 0.f), 65535.f);
        up[r] = (unsigned short)(int)uq;
      }
      *(ushort4*)&Y[YbaseA + yoff] = uv;
    }
    // qtile B
    {
      f32x4 cm = {0.f, 0.f, 0.f, 0.f}, cx = {0.f, 0.f, 0.f, 0.f};
      cm = __builtin_amdgcn_mfma_f32_16x16x32_f16(a0, xb0, cm, 0, 0, 0);
      cm = __builtin_amdgcn_mfma_f32_16x16x32_f16(a1, xb1, cm, 0, 0, 0);
      cx = __builtin_amdgcn_mfma_f32_16x16x32_f16(b0, xb0, cx, 0, 0, 0);
      cx = __builtin_amdgcn_mfma_f32_16x16x32_f16(a0, xlb0, cx, 0, 0, 0);
      cx = __builtin_amdgcn_mfma_f32_16x16x32_f16(b1, xb1, cx, 0, 0, 0);
      cx = __builtin_amdgcn_mfma_f32_16x16x32_f16(a1, xlb1, cx, 0, 0, 0);
      ushort4 uv;
      unsigned short* up = (unsigned short*)&uv;
#pragma unroll
      for (int r = 0; r < 4; ++r) {
        float s = fmaf(cx[r], 0.001953125f, cm[r]);
        float uq = fmaf(s, 8192.0f, qcB);
        uq = fminf(fmaxf(uq, 0.f), 65535.f);
        up[r] = (unsigned short)(int)uq;
      }
      *(ushort4*)&Y[YbaseB + yoff] = uv;
    }
  }
}

// ---- S2: entmax tau — slice-block COALESCED reads (fixes 1.57 TB/s) ----
// Block = (bh,qtile) slice: 16 rows x 8192 keys = 256KB contiguous. Thread
// t reads 4 coalesced 64B pieces (stride 64KB); all pieces belong to row
// t%16 by layout. 16 parallel row-reductions via shfl_xor(16,32) +
// LDS[w][16]. Math identical to R11 cascade (max + 5 bisect + 3 Michelot).
__global__ __launch_bounds__(1024) void hop_tau_kernel(
    const unsigned short* __restrict__ Y, float* __restrict__ tau) {
  const int b = blockIdx.x;  // bh*32 + qtile
  const size_t sb = (size_t)b * 131072;
  const int t = threadIdx.x;
  const int w = t >> 6, l = t & 63;
  const int r = t & 15;

  __shared__ float redm[16][16];
  __shared__ float rbis[5][16][16];
  __shared__ float rref[3][3][16][16];

  const uint4* p0 = (const uint4*)(Y + sb + (size_t)t * 32);
  const uint4* p1 = (const uint4*)(Y + sb + (size_t)t * 32 + 32768);
  const uint4* p2 = (const uint4*)(Y + sb + (size_t)t * 32 + 65536);
  const uint4* p3 = (const uint4*)(Y + sb + (size_t)t * 32 + 98304);
  uint4 q0 = p0[0], q1 = p0[1], q2 = p0[2], q3 = p0[3];
  uint4 q4 = p1[0], q5 = p1[1], q6 = p1[2], q7 = p1[3];
  uint4 q8 = p2[0], q9 = p2[1], q10 = p2[2], q11 = p2[3];
  uint4 q12 = p3[0], q13 = p3[1], q14 = p3[2], q15 = p3[3];

#define EACH_DW(OP)                                                          \
  OP(q0.x) OP(q0.y) OP(q0.z) OP(q0.w) OP(q1.x) OP(q1.y) OP(q1.z) OP(q1.w)    \
  OP(q2.x) OP(q2.y) OP(q2.z) OP(q2.w) OP(q3.x) OP(q3.y) OP(q3.z) OP(q3.w)    \
  OP(q4.x) OP(q4.y) OP(q4.z) OP(q4.w) OP(q5.x) OP(q5.y) OP(q5.z) OP(q5.w)    \
  OP(q6.x) OP(q6.y) OP(q6.z) OP(q6.w) OP(q7.x) OP(q7.y) OP(q7.z) OP(q7.w)    \
  OP(q8.x) OP(q8.y) OP(q8.z) OP(q8.w) OP(q9.x) OP(q9.y) OP(q9.z) OP(q9.w)    \
  OP(q10.x) OP(q10.y) OP(q10.z) OP(q10.w)                                    \
  OP(q11.x) OP(q11.y) OP(q11.z) OP(q11.w)                                    \
  OP(q12.x) OP(q12.y) OP(q12.z) OP(q12.w)                                    \
  OP(q13.x) OP(q13.y) OP(q13.z) OP(q13.w)                                    \
  OP(q14.x) OP(q14.y) OP(q14.z) OP(q14.w)                                    \
  OP(q15.x) OP(q15.y) OP(q15.z) OP(q15.w)

  // pass 0: exact row max (integer domain, then convert)
  unsigned um = 0;
#define OPMX(u) { unsigned a = (u) & 0xffffu, bb = (u) >> 16;                \
                  if (a > um) um = a; if (bb > um) um = bb; }
  EACH_DW(OPMX)
#undef OPMX
  float my = (float)um;
  my = fmaxf(my, __shfl_xor(my, 16, 64));
  my = fmaxf(my, __shfl_xor(my, 32, 64));
  if (l < 16) redm[w][l] = my;
  __syncthreads();
  float umaxf = redm[0][r];
#pragma unroll
  for (int ww = 1; ww < 16; ++ww) umaxf = fmaxf(umaxf, redm[ww][r]);
  const float ymax = fmaf(umaxf, QINV, -QOFF);

  // passes 1-5: bisection on [ymax-1.001, ymax] (f(lo) >= 1 by theorem)
  float lo = ymax - 1.001f, hi = ymax;
#pragma unroll 1
  for (int it = 0; it < 5; ++it) {
    float tv = 0.5f * (lo + hi);
    float f = 0.f;
#define OPBI(u) { float y0 = fmaf((float)((u) & 0xffffu), QINV, -QOFF);      \
                  float y1 = fmaf((float)((u) >> 16), QINV, -QOFF);          \
                  float d0 = fmaxf(y0 - tv, 0.f);                            \
                  float d1 = fmaxf(y1 - tv, 0.f);                            \
                  f = fmaf(d0, d0, f); f = fmaf(d1, d1, f); }
    EACH_DW(OPBI)
#undef OPBI
    f += __shfl_xor(f, 16, 64);
    f += __shfl_xor(f, 32, 64);
    if (l < 16) rbis[it][w][l] = f;
    __syncthreads();
    float tot = 0.f;
#pragma unroll
    for (int ww = 0; ww < 16; ++ww) tot += rbis[it][ww][r];
    if (tot >= 1.f) lo = tv; else hi = tv;
  }

  // passes 6-8: exact support refinements from the superset {y > lo}
  float tc = lo;
#pragma unroll 1
  for (int it = 0; it < 3; ++it) {
    float kk = 0.f, s1 = 0.f, s2 = 0.f;
#define OPRF(u) { float y0 = fmaf((float)((u) & 0xffffu), QINV, -QOFF);      \
                  float y1 = fmaf((float)((u) >> 16), QINV, -QOFF);          \
                  if (y0 > tc) { kk += 1.f; s1 += y0; s2 = fmaf(y0, y0, s2); } \
                  if (y1 > tc) { kk += 1.f; s1 += y1; s2 = fmaf(y1, y1, s2); } }
    EACH_DW(OPRF)
#undef OPRF
    kk += __shfl_xor(kk, 16, 64);
    kk += __shfl_xor(kk, 32, 64);
    s1 += __shfl_xor(s1, 16, 64);
    s1 += __shfl_xor(s1, 32, 64);
    s2 += __shfl_xor(s2, 16, 64);
    s2 += __shfl_xor(s2, 32, 64);
    if (l < 16) {
      rref[it][0][w][l] = kk;
      rref[it][1][w][l] = s1;
      rref[it][2][w][l] = s2;
    }
    __syncthreads();
    float K = 0.f, S1 = 0.f, S2 = 0.f;
#pragma unroll
    for (int ww = 0; ww < 16; ++ww) {
      K += rref[it][0][ww][r];
      S1 += rref[it][1][ww][r];
      S2 += rref[it][2][ww][r];
    }
    if (K >= 0.5f) {
      float mean = S1 / K;
      float ss = fmaf(-mean, S1, S2);
      float delta = (1.f - ss) / K;
      tc = delta > 0.f ? mean - sqrtf(delta) : mean;
    }
  }
#undef EACH_DW
  if (t < 16) {
    const int bh = b >> 5, qtile = b & 31;
    tau[bh * 512 + qtile * 16 + t] = tc;
  }
}

// ---------------- S3: weights + PV MFMA (1024 thr / 16 waves) ------------
__global__ __launch_bounds__(1024) void hop_pv_kernel(
    const unsigned short* __restrict__ Y, const f16x8* __restrict__ Vp,
    const float* __restrict__ tau, float* __restrict__ xi_out) {
  __shared__ float outp[16][16][64];
  __shared__ float taus[16];
  const int tid = threadIdx.x;
  const int w = tid >> 6, l = tid & 63;
  const int ql = l & 15, g = l >> 4;
  const int bh = blockIdx.x & 7, qtile = blockIdx.x >> 3;
  const int h = bh & 3;
  const size_t base_io = ((size_t)bh * 512 + qtile * 16) * 64;

  if (tid < 16) taus[tid] = tau[bh * 512 + qtile * 16 + tid];
  __syncthreads();
  const float t1 = taus[ql];
  const size_t Ybase = (size_t)(bh * 32 + qtile) * 131072;
  const f16x8* vb = Vp + (size_t)h * 65536 + l;

  f32x4 m2[4];
#pragma unroll
  for (int dt = 0; dt < 4; ++dt) m2[dt] = (f32x4){0.f, 0.f, 0.f, 0.f};

  for (int kc = 0; kc < 16; ++kc) {
    const int chunk = w * 16 + kc;
    uint4 uv = *(const uint4*)(Y + Ybase + (size_t)chunk * 512 + ql * 32 +
                               (g << 3));
    unsigned a[4] = {uv.x, uv.y, uv.z, uv.w};
    f16x8 a2;
#pragma unroll
    for (int e = 0; e < 4; ++e) {
      float y0 = fmaf((float)(a[e] & 0xffffu), QINV, -QOFF);
      float y1 = fmaf((float)(a[e] >> 16), QINV, -QOFF);
      float p0 = fmaxf(y0 - t1, 0.f);
      float p1 = fmaxf(y1 - t1, 0.f);
      a2[e * 2] = (f16)(p0 * p0);
      a2[e * 2 + 1] = (f16)(p1 * p1);
    }
#pragma unroll
    for (int dt = 0; dt < 4; ++dt) {
      f16x8 vf = vb[(((size_t)dt * 256 + chunk) << 6)];
      m2[dt] = __builtin_amdgcn_mfma_f32_16x16x32_f16(a2, vf, m2[dt], 0, 0, 0);
    }
  }
#pragma unroll
  for (int dt = 0; dt < 4; ++dt)
#pragma unroll
    for (int r = 0; r < 4; ++r)
      outp[w][(g << 2) + r][dt * 16 + ql] = m2[dt][r];
  __syncthreads();
  {
    float s = 0.f;
#pragma unroll
    for (int ww = 0; ww < 16; ++ww) s += outp[ww][tid >> 6][tid & 63];
    xi_out[base_io + tid] = s;
  }
}

// ---------------- converged copy ----------------
__global__ __launch_bounds__(256) void conv_copy_kernel(
    const float* __restrict__ xi, float* __restrict__ out) {
  int o4 = blockIdx.x * 256 + threadIdx.x;
  int o = o4 << 2;
  int dd = o & 63, hq = (o >> 6) & 3, sq = (o >> 8) & 511, bq = o >> 17;
  float4 v =
      *(const float4*)&xi[((((size_t)bq << 2) + hq) * 512 + sq) * 64 + dd];
  *(float4*)&out[o] = v;
}

extern "C" void kernel_launch(void* const* d_in, const int* in_sizes, int n_in,
                              void* d_out, int out_size, void* d_ws,
                              size_t ws_size, hipStream_t stream) {
  (void)in_sizes; (void)n_in; (void)out_size; (void)ws_size;
  const float* hidden = (const float*)d_in[0];
  const float* memory = (const float*)d_in[1];
  const float* Wq = (const float*)d_in[2];
  const float* Wk = (const float*)d_in[3];
  const float* Wv = (const float*)d_in[4];
  const float* Wo = (const float*)d_in[5];
  const float* log_beta = (const float*)d_in[6];
  const float* g_s = (const float*)d_in[7];
  const float* b_s = (const float*)d_in[8];
  const float* g_m = (const float*)d_in[9];
  const float* b_m = (const float*)d_in[10];
  float* out = (float*)d_out;

  float* ws = (float*)d_ws;
  float* mu_h = ws;                 // 1024
  float* rs_h = ws + 1024;          // 1024
  float* mu_m = ws + 2048;          // 8192
  float* rs_m = ws + 10240;         // 8192
  float* xiA = ws + 18432;          // 262144
  float* xiB = ws + 280576;         // 262144
  float* vb_q = ws + 542720;        // 256
  float* vb_k = ws + 542976;        // 256
  float* vb_v = ws + 543232;        // 256
  float* tau = ws + 543488;         // 4096
  f16x8* Khi = (f16x8*)(ws + 548864);  // 262144 f16x8 = 4MB
  f16x8* Klo = Khi + 262144;
  f16x8* Vp = Klo + 262144;
  f16x8* Bqh = Vp + 262144;         // 65536
  f16x8* Bql = Bqh + 65536;
  f16x8* Bkh = Bql + 65536;         // 32768
  f16x8* Bkl = Bkh + 32768;
  f16x8* Bvh = Bkl + 32768;
  f16x8* Bvl = Bvh + 32768;
  f16x8* Boh = Bvl + 32768;         // 65536
  f16x8* Bol = Boh + 65536;
  // Y (64MB) aliases the A-frag packs (stream-ordered, recomputed per call)
  unsigned short* Y = (unsigned short*)(Bol + 65536);
  f16x8* Amh = (f16x8*)Y;           // 16MB
  f16x8* Aml = Amh + 1048576;       // 16MB
  f16x8* Ahh = Aml + 1048576;       // 4MB
  f16x8* Ahl = Ahh + 262144;        // 4MB
  f16x8* Axh = Ahl + 262144;        // 0.5MB
  f16x8* Axl = Axh + 32768;         // 0.5MB

  ln_stats_all_kernel<<<9216, 256, 0, stream>>>(hidden, memory, mu_h, rs_h,
                                                mu_m, rs_m);
  hipMemsetAsync(vb_q, 0, 3 * 256 * sizeof(float), stream);

  split_a_all_kernel<<<5120, 256, 0, stream>>>(hidden, memory, mu_h, rs_h,
                                               mu_m, rs_m, Ahh, Ahl, Amh, Aml);
  split_w_all_kernel<<<768, 256, 0, stream>>>(Wq, Wk, Wv, Wo, g_s, g_m, Bqh,
                                              Bql, Bkh, Bkl, Bvh, Bvl, Boh,
                                              Bol);
  wcol3_kernel<<<dim3(1, 16, 3), 256, 0, stream>>>(Wq, b_s, Wk, b_m, Wv, b_m,
                                                   vb_q, vb_k, vb_v);

  gemm_mfma_kernel<<<dim3(4, 16), 256, 0, stream>>>(
      Ahh, Ahl, Bqh, Bql, vb_q, xiA, nullptr, nullptr, 1024, 256, 64, 0);
  gemm_mfma_kernel<<<dim3(4, 128), 256, 0, stream>>>(
      Amh, Aml, Bkh, Bkl, vb_k, nullptr, Khi, Klo, 8192, 256, 32, 4);
  gemm_mfma_kernel<<<dim3(4, 128), 256, 0, stream>>>(
      Amh, Aml, Bvh, Bvl, vb_v, nullptr, Vp, nullptr, 8192, 256, 32, 5);

  float* xin = xiA;
  float* xout = xiB;
  for (int step = 0; step < 3; ++step) {
    hop_score_kernel<<<256, 1024, 0, stream>>>(xin, Khi, Klo, log_beta, Y);
    hop_tau_kernel<<<256, 1024, 0, stream>>>(Y, tau);
    hop_pv_kernel<<<256, 1024, 0, stream>>>(Y, Vp, tau, xout);
    float* t = xin; xin = xout; xout = t;
  }

  split_a_kernel<<<128, 256, 0, stream>>>(xin, nullptr, nullptr, Axh, Axl,
                                          1024, 256, 1);
  gemm_mfma_kernel<<<dim3(32, 16), 256, 0, stream>>>(
      Axh, Axl, Boh, Bol, nullptr, out, nullptr, nullptr, 1024, 2048, 8, 3);
  conv_copy_kernel<<<256, 256, 0, stream>>>(xin, out + 2097152);
}

// Round 20
// 401.615 us; speedup vs baseline: 1.3250x; 1.3250x over previous
//
#include <hip/hip_runtime.h>
#include <math.h>

typedef _Float16 f16;
typedef f16 f16x8 __attribute__((ext_vector_type(8)));
typedef float f32x4 __attribute__((ext_vector_type(4)));

// quantization of y = s/2 - provisional_center: window [-2.5, +1.5]
#define QSCALE 16384.0f
#define QINV 6.103515625e-5f
#define QOFF 2.5f

__device__ __forceinline__ float wred_add(float v) {
#pragma unroll
  for (int off = 32; off >= 1; off >>= 1) v += __shfl_xor(v, off, 64);
  return v;
}
__device__ __forceinline__ float wred_max(float v) {
#pragma unroll
  for (int off = 32; off >= 1; off >>= 1) v = fmaxf(v, __shfl_xor(v, off, 64));
  return v;
}

// ---------------- LayerNorm row stats (hidden + memory in one launch) ----
__global__ __launch_bounds__(256) void ln_stats_all_kernel(
    const float* __restrict__ hidden, const float* __restrict__ memory,
    float* __restrict__ mu_h, float* __restrict__ rs_h,
    float* __restrict__ mu_m, float* __restrict__ rs_m) {
  int b = blockIdx.x, tid = threadIdx.x;
  const float* X;
  float* mu;
  float* rs;
  int cols, row;
  if (b < 1024) { X = hidden; cols = 2048; mu = mu_h; rs = rs_h; row = b; }
  else { X = memory; cols = 1024; mu = mu_m; rs = rs_m; row = b - 1024; }
  const float4* xr = (const float4*)(X + (size_t)row * cols);
  int nv = cols >> 10;
  float s = 0.f, s2 = 0.f;
  for (int v = 0; v < nv; ++v) {
    float4 x4 = xr[tid + (v << 8)];
    s += x4.x + x4.y + x4.z + x4.w;
    s2 += x4.x * x4.x + x4.y * x4.y + x4.z * x4.z + x4.w * x4.w;
  }
  s = wred_add(s);
  s2 = wred_add(s2);
  __shared__ float rb[8];
  int wid = tid >> 6, lane = tid & 63;
  if (lane == 0) { rb[wid] = s; rb[4 + wid] = s2; }
  __syncthreads();
  if (tid == 0) {
    float S = rb[0] + rb[1] + rb[2] + rb[3];
    float S2 = rb[4] + rb[5] + rb[6] + rb[7];
    float m = S / (float)cols;
    float var = S2 / (float)cols - m * m;
    mu[row] = m;
    rs[row] = 1.f / sqrtf(var + 1e-5f);
  }
}

// ---------------- split A (hidden + memory) in one launch ----------------
__global__ __launch_bounds__(256) void split_a_all_kernel(
    const float* __restrict__ hidden, const float* __restrict__ memory,
    const float* __restrict__ mu_h, const float* __restrict__ rs_h,
    const float* __restrict__ mu_m, const float* __restrict__ rs_m,
    f16x8* __restrict__ Ahh, f16x8* __restrict__ Ahl,
    f16x8* __restrict__ Amh, f16x8* __restrict__ Aml) {
  int b = blockIdx.x;
  const float* X;
  const float* mu;
  const float* rs;
  f16x8 *Ah, *Al;
  int M, Kd, b0;
  if (b < 1024) {
    X = hidden; mu = mu_h; rs = rs_h; Ah = Ahh; Al = Ahl;
    M = 1024; Kd = 2048; b0 = 0;
  } else {
    X = memory; mu = mu_m; rs = rs_m; Ah = Amh; Al = Aml;
    M = 8192; Kd = 1024; b0 = 1024;
  }
  int blk = (b - b0) * 4 + (threadIdx.x >> 6);
  int l = threadIdx.x & 63;
  int nmt = M >> 4;
  int kc = blk / nmt, mt = blk - kc * nmt;
  int m = mt * 16 + (l & 15);
  int k = kc * 32 + ((l >> 4) << 3);
  const float* src = X + (size_t)m * Kd + k;
  float mm = mu[m];
  float rr = rs[m];
  f16x8 hi, lo;
#pragma unroll
  for (int j = 0; j < 8; ++j) {
    float v = (src[j] - mm) * rr;
    f16 hv = (f16)v;
    hi[j] = hv;
    lo[j] = (f16)((v - (float)hv) * 512.f);
  }
  size_t o = ((size_t)blk << 6) + l;
  Ah[o] = hi;
  Al[o] = lo;
}

// ---------------- split A for xi (epilogue) ----------------
__global__ __launch_bounds__(256) void split_a_kernel(
    const float* __restrict__ X, const float* __restrict__ mu,
    const float* __restrict__ rs, f16x8* __restrict__ Ah,
    f16x8* __restrict__ Al, int M, int Kd, int lay) {
  int blk = blockIdx.x * 4 + (threadIdx.x >> 6);
  int l = threadIdx.x & 63;
  int nmt = M >> 4;
  int kc = blk / nmt, mt = blk - kc * nmt;
  int m = mt * 16 + (l & 15);
  int k = kc * 32 + ((l >> 4) << 3);
  const float* src;
  if (lay == 0) {
    src = X + (size_t)m * Kd + k;
  } else {
    int b = m >> 9, s = m & 511, hh = k >> 6, d = k & 63;
    src = X + ((((size_t)b * 4 + hh) * 512 + s) << 6) + d;
  }
  float mm = mu ? mu[m] : 0.f;
  float rr = rs ? rs[m] : 1.f;
  f16x8 hi, lo;
#pragma unroll
  for (int j = 0; j < 8; ++j) {
    float v = (src[j] - mm) * rr;
    f16 hv = (f16)v;
    hi[j] = hv;
    lo[j] = (f16)((v - (float)hv) * 512.f);
  }
  size_t o = ((size_t)blk << 6) + l;
  Ah[o] = hi;
  Al[o] = lo;
}

// ---------------- split W: all four weights in one launch ----------------
__global__ __launch_bounds__(256) void split_w_all_kernel(
    const float* __restrict__ Wq, const float* __restrict__ Wk,
    const float* __restrict__ Wv, const float* __restrict__ Wo,
    const float* __restrict__ g_s, const float* __restrict__ g_m,
    f16x8* __restrict__ Bqh, f16x8* __restrict__ Bql,
    f16x8* __restrict__ Bkh, f16x8* __restrict__ Bkl,
    f16x8* __restrict__ Bvh, f16x8* __restrict__ Bvl,
    f16x8* __restrict__ Boh, f16x8* __restrict__ Bol) {
  int b = blockIdx.x;
  const float* W;
  const float* g;
  f16x8 *Bh, *Bl;
  int N, base;
  if (b < 256) { W = Wq; g = g_s; Bh = Bqh; Bl = Bql; N = 256; base = 0; }
  else if (b < 384) { W = Wk; g = g_m; Bh = Bkh; Bl = Bkl; N = 256; base = 256; }
  else if (b < 512) { W = Wv; g = g_m; Bh = Bvh; Bl = Bvl; N = 256; base = 384; }
  else { W = Wo; g = nullptr; Bh = Boh; Bl = Bol; N = 2048; base = 512; }
  int blk = (b - base) * 4 + (threadIdx.x >> 6);
  int l = threadIdx.x & 63;
  int nnt = N >> 4;
  int kc = blk / nnt, nt = blk - kc * nnt;
  int n = nt * 16 + (l & 15);
  int k0 = kc * 32 + ((l >> 4) << 3);
  f16x8 hi, lo;
#pragma unroll
  for (int j = 0; j < 8; ++j) {
    float v = W[(size_t)(k0 + j) * N + n];
    if (g) v *= g[k0 + j];
    f16 hv = (f16)v;
    hi[j] = hv;
    lo[j] = (f16)((v - (float)hv) * 512.f);
  }
  size_t o = ((size_t)blk << 6) + l;
  Bh[o] = hi;
  Bl[o] = lo;
}

// ---------------- vb[t] = sum_k b[k]*W[k][t], 3 targets in one ----------
__global__ __launch_bounds__(256) void wcol3_kernel(
    const float* __restrict__ Wq, const float* __restrict__ bq,
    const float* __restrict__ Wk, const float* __restrict__ bk,
    const float* __restrict__ Wv, const float* __restrict__ bv,
    float* __restrict__ vbq, float* __restrict__ vbk,
    float* __restrict__ vbv) {
  int which = blockIdx.z;
  const float* W = which == 0 ? Wq : (which == 1 ? Wk : Wv);
  const float* b = which == 0 ? bq : (which == 1 ? bk : bv);
  float* vb = which == 0 ? vbq : (which == 1 ? vbk : vbv);
  int Kd = which == 0 ? 2048 : 1024;
  int t = threadIdx.x;
  int kpb = Kd >> 4;
  int k0 = blockIdx.y * kpb;
  float s = 0.f;
  for (int k = k0; k < k0 + kpb; ++k) s = fmaf(b[k], W[(size_t)k * 256 + t], s);
  atomicAdd(&vb[t], s);
}

// ---------------- split-f16 MFMA GEMM: C = A@W + vb ----------------
__global__ __launch_bounds__(256) void gemm_mfma_kernel(
    const f16x8* __restrict__ Ah, const f16x8* __restrict__ Al,
    const f16x8* __restrict__ Bh, const f16x8* __restrict__ Bl,
    const float* __restrict__ vb, float* __restrict__ outf,
    f16x8* __restrict__ o16a, f16x8* __restrict__ o16b, int M, int N, int nk,
    int out_mode) {
  __shared__ __align__(16) float Ts[64][68];
  const int tid = threadIdx.x;
  const int w = tid >> 6, l = tid & 63;
  const int ql = l & 15, g = l >> 4;
  const int bn = blockIdx.x, bm = blockIdx.y;
  const size_t astr = ((size_t)(M >> 4)) << 6;
  const size_t bstr = ((size_t)(N >> 4)) << 6;
  const f16x8* aph = Ah + (((size_t)(bm * 4 + w)) << 6) + l;
  const f16x8* apl = Al + (((size_t)(bm * 4 + w)) << 6) + l;
  const f16x8* bph = Bh + (((size_t)(bn * 4)) << 6) + l;
  const f16x8* bpl = Bl + (((size_t)(bn * 4)) << 6) + l;

  f32x4 cm[4], cx[4];
#pragma unroll
  for (int nf = 0; nf < 4; ++nf) {
    cm[nf] = (f32x4){0.f, 0.f, 0.f, 0.f};
    cx[nf] = (f32x4){0.f, 0.f, 0.f, 0.f};
  }

  f16x8 a0h = aph[0], a0l = apl[0];
  f16x8 b0h[4], b0l[4];
#pragma unroll
  for (int nf = 0; nf < 4; ++nf) {
    b0h[nf] = bph[nf << 6];
    b0l[nf] = bpl[nf << 6];
  }

  for (int kc = 0; kc < nk - 1; ++kc) {
    const size_t ao = (size_t)(kc + 1) * astr;
    const size_t bo = (size_t)(kc + 1) * bstr;
    f16x8 a1h = aph[ao], a1l = apl[ao];
    f16x8 b1h[4], b1l[4];
#pragma unroll
    for (int nf = 0; nf < 4; ++nf) {
      b1h[nf] = bph[bo + (nf << 6)];
      b1l[nf] = bpl[bo + (nf << 6)];
    }
#pragma unroll
    for (int nf = 0; nf < 4; ++nf) {
      cm[nf] = __builtin_amdgcn_mfma_f32_16x16x32_f16(a0h, b0h[nf], cm[nf], 0, 0, 0);
      cx[nf] = __builtin_amdgcn_mfma_f32_16x16x32_f16(a0h, b0l[nf], cx[nf], 0, 0, 0);
      cx[nf] = __builtin_amdgcn_mfma_f32_16x16x32_f16(a0l, b0h[nf], cx[nf], 0, 0, 0);
    }
    a0h = a1h;
    a0l = a1l;
#pragma unroll
    for (int nf = 0; nf < 4; ++nf) {
      b0h[nf] = b1h[nf];
      b0l[nf] = b1l[nf];
    }
  }
#pragma unroll
  for (int nf = 0; nf < 4; ++nf) {
    cm[nf] = __builtin_amdgcn_mfma_f32_16x16x32_f16(a0h, b0h[nf], cm[nf], 0, 0, 0);
    cx[nf] = __builtin_amdgcn_mfma_f32_16x16x32_f16(a0h, b0l[nf], cx[nf], 0, 0, 0);
    cx[nf] = __builtin_amdgcn_mfma_f32_16x16x32_f16(a0l, b0h[nf], cx[nf], 0, 0, 0);
  }

  float vbc[4] = {0.f, 0.f, 0.f, 0.f};
  if (vb) {
#pragma unroll
    for (int nf = 0; nf < 4; ++nf) vbc[nf] = vb[bn * 64 + nf * 16 + ql];
  }

  if (out_mode == 0) {
#pragma unroll
    for (int nf = 0; nf < 4; ++nf)
#pragma unroll
      for (int r = 0; r < 4; ++r) {
        float val = fmaf(cx[nf][r], 0.001953125f, cm[nf][r]) + vbc[nf];
        int m = bm * 64 + w * 16 + (g << 2) + r;
        int n = bn * 64 + nf * 16 + ql;
        int b = m >> 9, s = m & 511, hh = n >> 6, d = n & 63;
        outf[((((size_t)b * 4 + hh) * 512 + s) << 6) + d] = val;
      }
  } else if (out_mode == 3) {
#pragma unroll
    for (int nf = 0; nf < 4; ++nf)
#pragma unroll
      for (int r = 0; r < 4; ++r) {
        float val = fmaf(cx[nf][r], 0.001953125f, cm[nf][r]) + vbc[nf];
        int m = bm * 64 + w * 16 + (g << 2) + r;
        int n = bn * 64 + nf * 16 + ql;
        outf[(size_t)m * N + n] = val;
      }
  } else {
#pragma unroll
    for (int nf = 0; nf < 4; ++nf)
#pragma unroll
      for (int r = 0; r < 4; ++r)
        Ts[w * 16 + (g << 2) + r][nf * 16 + ql] =
            fmaf(cx[nf][r], 0.001953125f, cm[nf][r]) + vbc[nf];
    __syncthreads();
    if (out_mode == 4) {
#pragma unroll
      for (int i = 0; i < 2; ++i) {
        int slot = tid + (i << 8);
        int blk = slot >> 6, l2 = slot & 63;
        int ktl = blk >> 1, dc = blk & 1;
        int key = (ktl << 4) + (l2 & 15);
        int db = (dc << 5) + ((l2 >> 4) << 3);
        f16x8 hi, lo;
#pragma unroll
        for (int j = 0; j < 8; ++j) {
          float v = Ts[key][db + j];
          f16 hv = (f16)v;
          hi[j] = hv;
          lo[j] = (f16)((v - (float)hv) * 512.f);
        }
        size_t o = (((size_t)(bn * 512 + bm * 4 + ktl) * 2 + dc) << 6) + l2;
        o16a[o] = hi;
        o16b[o] = lo;
      }
    } else {
#pragma unroll
      for (int i = 0; i < 2; ++i) {
        int slot = tid + (i << 8);
        int blk = slot >> 6, l2 = slot & 63;
        int dt = blk >> 1, kcl = blk & 1;
        int keyb = (kcl << 5) + ((l2 >> 4) << 3);
        int d = (dt << 4) + (l2 & 15);
        f16x8 v8;
#pragma unroll
        for (int j = 0; j < 8; ++j) v8[j] = (f16)Ts[keyb + j][d];
        size_t o = (((size_t)(bn * 4 + dt) * 256 + bm * 2 + kcl) << 6) + l2;
        o16a[o] = v8;
      }
    }
  }
}

// ------- S1: scores; 2 qtiles (32 rows) x half the keys per block -------
__global__ __launch_bounds__(1024) void hop_score_kernel(
    const float* __restrict__ xi_in, const f16x8* __restrict__ Khi,
    const f16x8* __restrict__ Klo, const float* __restrict__ log_beta,
    unsigned short* __restrict__ Y) {
  __shared__ float xiq[32][64];
  __shared__ float mxb[16][32];
  __shared__ float mxs[32];
  const int tid = threadIdx.x;
  const int w = tid >> 6, l = tid & 63;
  const int ql = l & 15, g = l >> 4;
  const int bh = blockIdx.x & 7;
  const int qpair = (blockIdx.x >> 3) & 15;
  const int khalf = blockIdx.x >> 7;
  const int h = bh & 3;
  const size_t base_io = ((size_t)bh * 512 + qpair * 32) * 64;

  float beta = expf(log_beta[h]);
  for (int i = tid; i < 2048; i += 1024)
    xiq[i >> 6][i & 63] = xi_in[base_io + i] * beta;
  __syncthreads();

  f16x8 xa0, xa1, xla0, xla1;  // qtile A (rows ql)
  f16x8 xb0, xb1, xlb0, xlb1;  // qtile B (rows 16+ql)
#pragma unroll
  for (int j = 0; j < 8; ++j) {
    float a0v = xiq[ql][(g << 3) + j];
    float a1v = xiq[ql][32 + (g << 3) + j];
    float b0v = xiq[16 + ql][(g << 3) + j];
    float b1v = xiq[16 + ql][32 + (g << 3) + j];
    f16 ha0 = (f16)a0v, ha1 = (f16)a1v, hb0 = (f16)b0v, hb1 = (f16)b1v;
    xa0[j] = ha0; xla0[j] = (f16)((a0v - (float)ha0) * 512.f);
    xa1[j] = ha1; xla1[j] = (f16)((a1v - (float)ha1) * 512.f);
    xb0[j] = hb0; xlb0[j] = (f16)((b0v - (float)hb0) * 512.f);
    xb1[j] = hb1; xlb1[j] = (f16)((b1v - (float)hb1) * 512.f);
  }

  const f16x8* kb = Khi + (size_t)h * 65536 + l;
  const f16x8* kl = Klo + (size_t)h * 65536 + l;

  // sample at kt = w*32 (khalf-independent -> identical centers)
  {
    const int kts = w * 32;
    f16x8 sa0 = kb[(size_t)kts * 128], sa1 = kb[(size_t)kts * 128 + 64];
    f32x4 cA = {0.f, 0.f, 0.f, 0.f}, cB = {0.f, 0.f, 0.f, 0.f};
    cA = __builtin_amdgcn_mfma_f32_16x16x32_f16(sa0, xa0, cA, 0, 0, 0);
    cA = __builtin_amdgcn_mfma_f32_16x16x32_f16(sa1, xa1, cA, 0, 0, 0);
    cB = __builtin_amdgcn_mfma_f32_16x16x32_f16(sa0, xb0, cB, 0, 0, 0);
    cB = __builtin_amdgcn_mfma_f32_16x16x32_f16(sa1, xb1, cB, 0, 0, 0);
    float mA = fmaxf(fmaxf(cA[0], cA[1]), fmaxf(cA[2], cA[3]));
    float mB = fmaxf(fmaxf(cB[0], cB[1]), fmaxf(cB[2], cB[3]));
    mA = fmaxf(mA, __shfl_xor(mA, 16, 64));
    mA = fmaxf(mA, __shfl_xor(mA, 32, 64));
    mB = fmaxf(mB, __shfl_xor(mB, 16, 64));
    mB = fmaxf(mB, __shfl_xor(mB, 32, 64));
    if (l < 16) { mxb[w][ql] = mA; mxb[w][16 + ql] = mB; }
  }
  __syncthreads();
  if (tid < 32) {
    float m = mxb[0][tid];
#pragma unroll
    for (int ww = 1; ww < 16; ++ww) m = fmaxf(m, mxb[ww][tid]);
    mxs[tid] = m;
  }
  __syncthreads();
  const float qcA = QOFF * QSCALE + 0.5f - mxs[ql] * 0.5f * QSCALE;
  const float qcB = QOFF * QSCALE + 0.5f - mxs[16 + ql] * 0.5f * QSCALE;

  const size_t YbaseA = (size_t)(bh * 32 + qpair * 2) * 131072;
  const size_t YbaseB = YbaseA + 131072;
  const int kt0 = khalf * 256 + w * 16;
  for (int kt = kt0; kt < kt0 + 16; ++kt) {
    f16x8 a0 = kb[(size_t)kt * 128], a1 = kb[(size_t)kt * 128 + 64];
    f16x8 b0 = kl[(size_t)kt * 128], b1 = kl[(size_t)kt * 128 + 64];
    const size_t yoff =
        (size_t)(kt >> 1) * 512 + ql * 32 + (kt & 1) * 16 + (g << 2);
    // qtile A
    {
      f32x4 cm = {0.f, 0.f, 0.f, 0.f}, cx = {0.f, 0.f, 0.f, 0.f};
      cm = __builtin_amdgcn_mfma_f32_16x16x32_f16(a0, xa0, cm, 0, 0, 0);
      cm = __builtin_amdgcn_mfma_f32_16x16x32_f16(a1, xa1, cm, 0, 0, 0);
      cx = __builtin_amdgcn_mfma_f32_16x16x32_f16(b0, xa0, cx, 0, 0, 0);
      cx = __builtin_amdgcn_mfma_f32_16x16x32_f16(a0, xla0, cx, 0, 0, 0);
      cx = __builtin_amdgcn_mfma_f32_16x16x32_f16(b1, xa1, cx, 0, 0, 0);
      cx = __builtin_amdgcn_mfma_f32_16x16x32_f16(a1, xla1, cx, 0, 0, 0);
      ushort4 uv;
      unsigned short* up = (unsigned short*)&uv;
#pragma unroll
      for (int r = 0; r < 4; ++r) {
        float s = fmaf(cx[r], 0.001953125f, cm[r]);
        float uq = fmaf(s, 8192.0f, qcA);
        uq = fminf(fmaxf(uq, 0.f), 65535.f);
        up[r] = (unsigned short)(int)uq;
      }
      *(ushort4*)&Y[YbaseA + yoff] = uv;
    }
    // qtile B
    {
      f32x4 cm = {0.f, 0.f, 0.f, 0.f}, cx = {0.f, 0.f, 0.f, 0.f};
      cm = __builtin_amdgcn_mfma_f32_16x16x32_f16(a0, xb0, cm, 0, 0, 0);
      cm = __builtin_amdgcn_mfma_f32_16x16x32_f16(a1, xb1, cm, 0, 0, 0);
      cx = __builtin_amdgcn_mfma_f32_16x16x32_f16(b0, xb0, cx, 0, 0, 0);
      cx = __builtin_amdgcn_mfma_f32_16x16x32_f16(a0, xlb0, cx, 0, 0, 0);
      cx = __builtin_amdgcn_mfma_f32_16x16x32_f16(b1, xb1, cx, 0, 0, 0);
      cx = __builtin_amdgcn_mfma_f32_16x16x32_f16(a1, xlb1, cx, 0, 0, 0);
      ushort4 uv;
      unsigned short* up = (unsigned short*)&uv;
#pragma unroll
      for (int r = 0; r < 4; ++r) {
        float s = fmaf(cx[r], 0.001953125f, cm[r]);
        float uq = fmaf(s, 8192.0f, qcB);
        uq = fminf(fmaxf(uq, 0.f), 65535.f);
        up[r] = (unsigned short)(int)uq;
      }
      *(ushort4*)&Y[YbaseB + yoff] = uv;
    }
  }
}

// ---------------- S2: exact entmax tau (R11 measured-best, locked) -------
__global__ __launch_bounds__(256) void hop_tau_kernel(
    const unsigned short* __restrict__ Y, float* __restrict__ tau) {
  const int row = blockIdx.x;
  const int bh = row >> 9, qi = row & 511;
  const int qtile = qi >> 4, ql = qi & 15;
  const size_t yb = (size_t)(bh * 32 + qtile) * 131072 + ql * 32;
  const int t = threadIdx.x;
  const uint4* p = (const uint4*)(Y + yb + (size_t)t * 512);
  float y[32];
#pragma unroll
  for (int v = 0; v < 4; ++v) {
    uint4 u = p[v];
    unsigned a[4] = {u.x, u.y, u.z, u.w};
#pragma unroll
    for (int e = 0; e < 4; ++e) {
      y[v * 8 + e * 2] = fmaf((float)(a[e] & 0xffffu), QINV, -QOFF);
      y[v * 8 + e * 2 + 1] = fmaf((float)(a[e] >> 16), QINV, -QOFF);
    }
  }
  __shared__ float redm[4];
  __shared__ float rb[5][4];
  __shared__ float rb3[3][4][3];
  const int wi = t >> 6, lane = t & 63;

  // pass 0: exact row max
  {
    float m = y[0];
#pragma unroll
    for (int i = 1; i < 32; ++i) m = fmaxf(m, y[i]);
    m = wred_max(m);
    if (lane == 0) redm[wi] = m;
  }
  __syncthreads();
  const float ymax =
      fmaxf(fmaxf(redm[0], redm[1]), fmaxf(redm[2], redm[3]));

  // passes 1-5: bisection on [ymax-1, ymax] (f(lo) >= 1 by theorem)
  float lo = ymax - 1.001f, hi = ymax;
#pragma unroll 1
  for (int it = 0; it < 5; ++it) {
    float tv = 0.5f * (lo + hi);
    float f = 0.f;
#pragma unroll
    for (int i = 0; i < 32; ++i) {
      float d = fmaxf(y[i] - tv, 0.f);
      f = fmaf(d, d, f);
    }
    f = wred_add(f);
    if (lane == 0) rb[it][wi] = f;
    __syncthreads();
    float tot = rb[it][0] + rb[it][1] + rb[it][2] + rb[it][3];
    if (tot >= 1.f) lo = tv; else hi = tv;
  }

  // passes 6-8: exact support refinements from the superset {y > lo}
  float tc = lo;
#pragma unroll 1
  for (int it = 0; it < 3; ++it) {
    float kk = 0.f, s1 = 0.f, s2 = 0.f;
#pragma unroll
    for (int i = 0; i < 32; ++i) {
      if (y[i] > tc) { kk += 1.f; s1 += y[i]; s2 = fmaf(y[i], y[i], s2); }
    }
    kk = wred_add(kk);
    s1 = wred_add(s1);
    s2 = wred_add(s2);
    if (lane == 0) { rb3[it][wi][0] = kk; rb3[it][wi][1] = s1; rb3[it][wi][2] = s2; }
    __syncthreads();
    float K = rb3[it][0][0] + rb3[it][1][0] + rb3[it][2][0] + rb3[it][3][0];
    float S1 = rb3[it][0][1] + rb3[it][1][1] + rb3[it][2][1] + rb3[it][3][1];
    float S2 = rb3[it][0][2] + rb3[it][1][2] + rb3[it][2][2] + rb3[it][3][2];
    if (K >= 0.5f) {
      float mean = S1 / K;
      float ss = fmaf(-mean, S1, S2);
      float delta = (1.f - ss) / K;
      tc = delta > 0.f ? mean - sqrtf(delta) : mean;
    }
  }
  if (t == 0) tau[row] = tc;
}

// ---------------- S3: weights + PV MFMA (1024 thr / 16 waves) ------------
__global__ __launch_bounds__(1024) void hop_pv_kernel(
    const unsigned short* __restrict__ Y, const f16x8* __restrict__ Vp,
    const float* __restrict__ tau, float* __restrict__ xi_out) {
  __shared__ float outp[16][16][64];
  __shared__ float taus[16];
  const int tid = threadIdx.x;
  const int w = tid >> 6, l = tid & 63;
  const int ql = l & 15, g = l >> 4;
  const int bh = blockIdx.x & 7, qtile = blockIdx.x >> 3;
  const int h = bh & 3;
  const size_t base_io = ((size_t)bh * 512 + qtile * 16) * 64;

  if (tid < 16) taus[tid] = tau[bh * 512 + qtile * 16 + tid];
  __syncthreads();
  const float t1 = taus[ql];
  const size_t Ybase = (size_t)(bh * 32 + qtile) * 131072;
  const f16x8* vb = Vp + (size_t)h * 65536 + l;

  f32x4 m2[4];
#pragma unroll
  for (int dt = 0; dt < 4; ++dt) m2[dt] = (f32x4){0.f, 0.f, 0.f, 0.f};

  for (int kc = 0; kc < 16; ++kc) {
    const int chunk = w * 16 + kc;
    uint4 uv = *(const uint4*)(Y + Ybase + (size_t)chunk * 512 + ql * 32 +
                               (g << 3));
    unsigned a[4] = {uv.x, uv.y, uv.z, uv.w};
    f16x8 a2;
#pragma unroll
    for (int e = 0; e < 4; ++e) {
      float y0 = fmaf((float)(a[e] & 0xffffu), QINV, -QOFF);
      float y1 = fmaf((float)(a[e] >> 16), QINV, -QOFF);
      float p0 = fmaxf(y0 - t1, 0.f);
      float p1 = fmaxf(y1 - t1, 0.f);
      a2[e * 2] = (f16)(p0 * p0);
      a2[e * 2 + 1] = (f16)(p1 * p1);
    }
#pragma unroll
    for (int dt = 0; dt < 4; ++dt) {
      f16x8 vf = vb[(((size_t)dt * 256 + chunk) << 6)];
      m2[dt] = __builtin_amdgcn_mfma_f32_16x16x32_f16(a2, vf, m2[dt], 0, 0, 0);
    }
  }
#pragma unroll
  for (int dt = 0; dt < 4; ++dt)
#pragma unroll
    for (int r = 0; r < 4; ++r)
      outp[w][(g << 2) + r][dt * 16 + ql] = m2[dt][r];
  __syncthreads();
  {
    float s = 0.f;
#pragma unroll
    for (int ww = 0; ww < 16; ++ww) s += outp[ww][tid >> 6][tid & 63];
    xi_out[base_io + tid] = s;
  }
}

// ---------------- converged copy ----------------
__global__ __launch_bounds__(256) void conv_copy_kernel(
    const float* __restrict__ xi, float* __restrict__ out) {
  int o4 = blockIdx.x * 256 + threadIdx.x;
  int o = o4 << 2;
  int dd = o & 63, hq = (o >> 6) & 3, sq = (o >> 8) & 511, bq = o >> 17;
  float4 v =
      *(const float4*)&xi[((((size_t)bq << 2) + hq) * 512 + sq) * 64 + dd];
  *(float4*)&out[o] = v;
}

extern "C" void kernel_launch(void* const* d_in, const int* in_sizes, int n_in,
                              void* d_out, int out_size, void* d_ws,
                              size_t ws_size, hipStream_t stream) {
  (void)in_sizes; (void)n_in; (void)out_size; (void)ws_size;
  const float* hidden = (const float*)d_in[0];
  const float* memory = (const float*)d_in[1];
  const float* Wq = (const float*)d_in[2];
  const float* Wk = (const float*)d_in[3];
  const float* Wv = (const float*)d_in[4];
  const float* Wo = (const float*)d_in[5];
  const float* log_beta = (const float*)d_in[6];
  const float* g_s = (const float*)d_in[7];
  const float* b_s = (const float*)d_in[8];
  const float* g_m = (const float*)d_in[9];
  const float* b_m = (const float*)d_in[10];
  float* out = (float*)d_out;

  float* ws = (float*)d_ws;
  float* mu_h = ws;                 // 1024
  float* rs_h = ws + 1024;          // 1024
  float* mu_m = ws + 2048;          // 8192
  float* rs_m = ws + 10240;         // 8192
  float* xiA = ws + 18432;          // 262144
  float* xiB = ws + 280576;         // 262144
  float* vb_q = ws + 542720;        // 256
  float* vb_k = ws + 542976;        // 256
  float* vb_v = ws + 543232;        // 256
  float* tau = ws + 543488;         // 4096
  f16x8* Khi = (f16x8*)(ws + 548864);  // 262144 f16x8 = 4MB
  f16x8* Klo = Khi + 262144;
  f16x8* Vp = Klo + 262144;
  f16x8* Bqh = Vp + 262144;         // 65536
  f16x8* Bql = Bqh + 65536;
  f16x8* Bkh = Bql + 65536;         // 32768
  f16x8* Bkl = Bkh + 32768;
  f16x8* Bvh = Bkl + 32768;
  f16x8* Bvl = Bvh + 32768;
  f16x8* Boh = Bvl + 32768;         // 65536
  f16x8* Bol = Boh + 65536;
  // Y (64MB) aliases the A-frag packs (stream-ordered, recomputed per call)
  unsigned short* Y = (unsigned short*)(Bol + 65536);
  f16x8* Amh = (f16x8*)Y;           // 16MB
  f16x8* Aml = Amh + 1048576;       // 16MB
  f16x8* Ahh = Aml + 1048576;       // 4MB
  f16x8* Ahl = Ahh + 262144;        // 4MB
  f16x8* Axh = Ahl + 262144;        // 0.5MB
  f16x8* Axl = Axh + 32768;         // 0.5MB

  ln_stats_all_kernel<<<9216, 256, 0, stream>>>(hidden, memory, mu_h, rs_h,
                                                mu_m, rs_m);
  hipMemsetAsync(vb_q, 0, 3 * 256 * sizeof(float), stream);

  split_a_all_kernel<<<5120, 256, 0, stream>>>(hidden, memory, mu_h, rs_h,
                                               mu_m, rs_m, Ahh, Ahl, Amh, Aml);
  split_w_all_kernel<<<768, 256, 0, stream>>>(Wq, Wk, Wv, Wo, g_s, g_m, Bqh,
                                              Bql, Bkh, Bkl, Bvh, Bvl, Boh,
                                              Bol);
  wcol3_kernel<<<dim3(1, 16, 3), 256, 0, stream>>>(Wq, b_s, Wk, b_m, Wv, b_m,
                                                   vb_q, vb_k, vb_v);

  gemm_mfma_kernel<<<dim3(4, 16), 256, 0, stream>>>(
      Ahh, Ahl, Bqh, Bql, vb_q, xiA, nullptr, nullptr, 1024, 256, 64, 0);
  gemm_mfma_kernel<<<dim3(4, 128), 256, 0, stream>>>(
      Amh, Aml, Bkh, Bkl, vb_k, nullptr, Khi, Klo, 8192, 256, 32, 4);
  gemm_mfma_kernel<<<dim3(4, 128), 256, 0, stream>>>(
      Amh, Aml, Bvh, Bvl, vb_v, nullptr, Vp, nullptr, 8192, 256, 32, 5);

  float* xin = xiA;
  float* xout = xiB;
  for (int step = 0; step < 3; ++step) {
    hop_score_kernel<<<256, 1024, 0, stream>>>(xin, Khi, Klo, log_beta, Y);
    hop_tau_kernel<<<4096, 256, 0, stream>>>(Y, tau);
    hop_pv_kernel<<<256, 1024, 0, stream>>>(Y, Vp, tau, xout);
    float* t = xin; xin = xout; xout = t;
  }

  split_a_kernel<<<128, 256, 0, stream>>>(xin, nullptr, nullptr, Axh, Axl,
                                          1024, 256, 1);
  gemm_mfma_kernel<<<dim3(32, 16), 256, 0, stream>>>(
      Axh, Axl, Boh, Bol, nullptr, out, nullptr, nullptr, 1024, 2048, 8, 3);
  conv_copy_kernel<<<256, 256, 0, stream>>>(xin, out + 2097152);
}